// Round 4
// baseline (17.582 us; speedup 1.0000x reference)
//
#include <hip/hip_runtime.h>
#include <hip/hip_bf16.h>

#define VOCAB 50257
#define DIM 512
#define PAD_IDX 0
#define F4_PER_ROW (DIM / 4)   // 128
#define UNROLL 8

typedef float f32x4 __attribute__((ext_vector_type(4)));

// out[t, :] = raw_weight[x[t], :] * mask[x[t]]   (zero when x[t]==PAD_IDX)
//
// Each wave's 64 lanes cover 64 consecutive float4 = half a weight row, so
// row = g>>7 is wave-uniform. readfirstlane makes that provable -> x[row]
// and mask[idx] become scalar s_loads (constant cache, lgkmcnt path),
// leaving the vmcnt queue entirely for the 8 independent w-gathers and 8
// nontemporal stores per thread. Grid 1024x256, unroll 8: 16 waves/CU x 8
// outstanding 16B gathers.
__global__ __launch_bounds__(256) void vdemb_kernel(
    const int* __restrict__ x,
    const float* __restrict__ w,
    const float* __restrict__ mask,
    float* __restrict__ out,
    int n_float4)
{
    const int stride = gridDim.x * blockDim.x;
    const int g0 = blockIdx.x * blockDim.x + threadIdx.x;
    const f32x4* __restrict__ w4 = reinterpret_cast<const f32x4*>(w);
    f32x4* __restrict__ o4 = reinterpret_cast<f32x4*>(out);

    if (g0 + (UNROLL - 1) * stride < n_float4) {
        // fast path: exact fit for the shipped shape (2048*256*... ) — all
        // UNROLL chunks in range, no bounds checks.
        int   idx[UNROLL];
        float scl[UNROLL];
        f32x4 v[UNROLL];
#pragma unroll
        for (int i = 0; i < UNROLL; ++i) {
            int g = g0 + i * stride;
            int row = __builtin_amdgcn_readfirstlane(g >> 7);  // wave-uniform
            idx[i] = x[row];                                   // s_load
        }
#pragma unroll
        for (int i = 0; i < UNROLL; ++i) {
            scl[i] = (idx[i] != PAD_IDX) ? mask[idx[i]] : 0.0f; // s_load
        }
#pragma unroll
        for (int i = 0; i < UNROLL; ++i) {
            int g = g0 + i * stride;
            v[i] = w4[(size_t)idx[i] * F4_PER_ROW + (g & 127)]; // vector gather
        }
#pragma unroll
        for (int i = 0; i < UNROLL; ++i) {
            int g = g0 + i * stride;
            f32x4 r = v[i] * scl[i];
            __builtin_nontemporal_store(r, &o4[g]);
        }
    } else {
        // tail path (shapes that don't divide evenly)
        for (int g = g0; g < n_float4; g += stride) {
            int row = g >> 7;
            int ix = x[row];
            float s = (ix != PAD_IDX) ? mask[ix] : 0.0f;
            f32x4 v = w4[(size_t)ix * F4_PER_ROW + (g & 127)];
            v *= s;
            __builtin_nontemporal_store(v, &o4[g]);
        }
    }
}

extern "C" void kernel_launch(void* const* d_in, const int* in_sizes, int n_in,
                              void* d_out, int out_size, void* d_ws, size_t ws_size,
                              hipStream_t stream) {
    const int*   x    = (const int*)d_in[0];     // 8*2048 token ids
    const float* w    = (const float*)d_in[1];   // 50257*512 fp32
    const float* mask = (const float*)d_in[2];   // 50257 fp32
    float* out = (float*)d_out;

    int tokens = in_sizes[0];                    // 16384
    int n_float4 = tokens * F4_PER_ROW;          // 2,097,152

    const int block = 256;
    int grid = (n_float4 + block * UNROLL - 1) / (block * UNROLL);  // 1024
    vdemb_kernel<<<grid, block, 0, stream>>>(x, w, mask, out, n_float4);
}

// Round 5
// 15.466 us; speedup vs baseline: 1.1368x; 1.1368x over previous
//
#include <hip/hip_runtime.h>
#include <hip/hip_bf16.h>

#define VOCAB 50257
#define DIM 512
#define PAD_IDX 0
#define F4_PER_ROW (DIM / 4)   // 128
#define UNROLL 4

typedef float f32x4 __attribute__((ext_vector_type(4)));

// out[t, :] = raw_weight[x[t], :] * mask[x[t]]   (zero when x[t]==PAD_IDX)
//
// Round-3 structure (best: 15.8us): grid-stride hard-unrolled x4, vector
// (per-lane) index/mask loads -- HW coalesces the wave-uniform address into
// one request + broadcast; the round-4 readfirstlane/s_load variant
// serialized on lgkmcnt and regressed. Nontemporal stores keep the
// write-once output from thrashing L2. block=512 halves block count vs
// round 3 (dispatch ramp); x loads hoisted to the top so the 2-level
// gather chain (x -> w) starts immediately at wave launch.
__global__ __launch_bounds__(512) void vdemb_kernel(
    const int* __restrict__ x,
    const float* __restrict__ w,
    const float* __restrict__ mask,
    float* __restrict__ out,
    int n_float4)
{
    const int stride = gridDim.x * blockDim.x;
    const int g0 = blockIdx.x * blockDim.x + threadIdx.x;
    const f32x4* __restrict__ w4 = reinterpret_cast<const f32x4*>(w);
    f32x4* __restrict__ o4 = reinterpret_cast<f32x4*>(out);

    if (g0 + (UNROLL - 1) * stride < n_float4) {
        // fast path: exact fit for the shipped shape, no bounds checks
        int idx[UNROLL];
#pragma unroll
        for (int i = 0; i < UNROLL; ++i)
            idx[i] = x[(g0 + i * stride) >> 7];      // issue all index loads first

        float scl[UNROLL];
        f32x4 v[UNROLL];
#pragma unroll
        for (int i = 0; i < UNROLL; ++i)
            scl[i] = (idx[i] != PAD_IDX) ? mask[idx[i]] : 0.0f;
#pragma unroll
        for (int i = 0; i < UNROLL; ++i) {
            int g = g0 + i * stride;
            v[i] = w4[(size_t)idx[i] * F4_PER_ROW + (g & 127)];
        }
#pragma unroll
        for (int i = 0; i < UNROLL; ++i) {
            f32x4 r = v[i] * scl[i];
            __builtin_nontemporal_store(r, &o4[g0 + i * stride]);
        }
    } else {
        // tail path (shapes that don't divide evenly)
        for (int g = g0; g < n_float4; g += stride) {
            int ix = x[g >> 7];
            float s = (ix != PAD_IDX) ? mask[ix] : 0.0f;
            f32x4 v = w4[(size_t)ix * F4_PER_ROW + (g & 127)];
            v *= s;
            __builtin_nontemporal_store(v, &o4[g]);
        }
    }
}

extern "C" void kernel_launch(void* const* d_in, const int* in_sizes, int n_in,
                              void* d_out, int out_size, void* d_ws, size_t ws_size,
                              hipStream_t stream) {
    const int*   x    = (const int*)d_in[0];     // 8*2048 token ids
    const float* w    = (const float*)d_in[1];   // 50257*512 fp32
    const float* mask = (const float*)d_in[2];   // 50257 fp32
    float* out = (float*)d_out;

    int tokens = in_sizes[0];                    // 16384
    int n_float4 = tokens * F4_PER_ROW;          // 2,097,152

    const int block = 512;
    int grid = (n_float4 + block * UNROLL - 1) / (block * UNROLL);  // 1024
    vdemb_kernel<<<grid, block, 0, stream>>>(x, w, mask, out, n_float4);
}